// Round 2
// baseline (92.812 us; speedup 1.0000x reference)
//
#include <hip/hip_runtime.h>
#include <hip/hip_cooperative_groups.h>

namespace cg = cooperative_groups;

// out[0..255] = 0.5 * mean(sigmoid(conv2d_valid(data, w4x4) + b))
// Quantum term is identically 0: RX(pi) = -i*X is a global phase on the
// uniform H^16|0> state, CX is a basis permutation -> uniform probs ->
// 2*P(q0=1)-1 = 0 exactly.
//
// Single cooperative dispatch (was 2 dispatches; round-1's spin-wait fusion
// hung the container -- replaced with the sanctioned grid.sync() mechanism):
//   * 256 blocks, block b computes the partial sigmoid-sum of image b
//     (4 adjacent pixels/step via two aligned float4 LDS reads per kernel
//     row: 8x ds_read_b128 + 64 FMA per group), stores partial to ws[b].
//   * grid.sync() (cooperative launch -> HW-validated co-residency +
//     device-scope fence; no polling, no residency assumptions).
//   * Block 0 reduces the 256 partials and broadcasts to out[0..255].
// Fallback: if hipLaunchCooperativeKernel is rejected, launch the proven
// two-kernel version (known-good 60 us) instead of failing.

constexpr int IMG   = 64;
constexpr int OUTW  = 61;                   // 64 - 4 + 1
constexpr int NPIX  = OUTW * OUTW;          // 3721
constexpr int BATCH = 256;
constexpr int GPR   = 16;                   // 4-pixel groups per row (j0 = 4g)
constexpr int NGRP  = OUTW * GPR;           // 976
constexpr float INV_TOTAL = 1.0f / (float)(BATCH * NPIX);

__device__ __forceinline__ float sigf(float s) {
    return __builtin_amdgcn_rcpf(1.0f + __expf(-s));
}

// Shared conv+sigmoid partial for one image; returns block partial on tid 0.
__device__ __forceinline__ float conv_partial(
    const float* __restrict__ data, const float* __restrict__ w,
    const float* __restrict__ bias)
{
    __shared__ __align__(16) float img[IMG * IMG + 4];  // +4 pad: g=15 second f4
    __shared__ float wsm[16];
    __shared__ float wave_part[4];

    const int tid = threadIdx.x;

    // Stage image: 1024 float4 over 256 threads (coalesced 16B/lane).
    const float* src = data + (size_t)blockIdx.x * (IMG * IMG);
    #pragma unroll
    for (int i = 0; i < 4; ++i)
        reinterpret_cast<float4*>(img)[tid + 256 * i] =
            reinterpret_cast<const float4*>(src)[tid + 256 * i];
    if (tid < 16) wsm[tid] = w[tid];
    if (tid >= 16 && tid < 20) img[IMG * IMG + tid - 16] = 0.0f;  // pad
    __syncthreads();

    // Weights to registers (uniform LDS reads broadcast, conflict-free).
    float wr[16];
    #pragma unroll
    for (int k = 0; k < 16; ++k) wr[k] = wsm[k];
    const float b0 = bias[0];

    const float4* imgv = reinterpret_cast<const float4*>(img);
    float acc = 0.0f;

    for (int gidx = tid; gidx < NGRP; gidx += 256) {
        const int i = gidx >> 4;          // output row
        const int g = gidx & 15;          // 4-pixel group; j0 = 4g
        float s0 = b0, s1 = b0, s2 = b0, s3 = b0;
        #pragma unroll
        for (int ki = 0; ki < 4; ++ki) {
            const int rb = (i + ki) * (IMG / 4) + g;
            const float4 a = imgv[rb];        // cols 4g .. 4g+3
            const float4 c = imgv[rb + 1];    // cols 4g+4 .. 4g+7 (pad-safe)
            const float w0 = wr[ki * 4 + 0], w1 = wr[ki * 4 + 1];
            const float w2 = wr[ki * 4 + 2], w3 = wr[ki * 4 + 3];
            s0 = fmaf(a.x, w0, fmaf(a.y, w1, fmaf(a.z, w2, fmaf(a.w, w3, s0))));
            s1 = fmaf(a.y, w0, fmaf(a.z, w1, fmaf(a.w, w2, fmaf(c.x, w3, s1))));
            s2 = fmaf(a.z, w0, fmaf(a.w, w1, fmaf(c.x, w2, fmaf(c.y, w3, s2))));
            s3 = fmaf(a.w, w0, fmaf(c.x, w1, fmaf(c.y, w2, fmaf(c.z, w3, s3))));
        }
        if (g == 15) {                    // j0=60: only pixel 0 in range (OUTW=61)
            acc += sigf(s0);
        } else {
            acc += sigf(s0) + sigf(s1) + sigf(s2) + sigf(s3);
        }
    }

    // Wave-64 shuffle reduction, then cross-wave via LDS.
    #pragma unroll
    for (int off = 32; off > 0; off >>= 1)
        acc += __shfl_down(acc, off, 64);
    if ((tid & 63) == 0) wave_part[tid >> 6] = acc;
    __syncthreads();

    return wave_part[0] + wave_part[1] + wave_part[2] + wave_part[3];
}

// ---- Path A: single cooperative kernel ------------------------------------
__global__ __launch_bounds__(256) void conv_sig_coop(
    const float* __restrict__ data, const float* __restrict__ w,
    const float* __restrict__ bias, float* __restrict__ ws,
    float* __restrict__ out)
{
    const int tid = threadIdx.x;
    const float p = conv_partial(data, w, bias);
    if (tid == 0) ws[blockIdx.x] = p;

    cg::this_grid().sync();               // device-scope fence + grid barrier

    if (blockIdx.x != 0) return;

    __shared__ float wave_part2[4];
    __shared__ float bcast;
    float v = ws[tid];
    #pragma unroll
    for (int off = 32; off > 0; off >>= 1)
        v += __shfl_down(v, off, 64);
    if ((tid & 63) == 0) wave_part2[tid >> 6] = v;
    __syncthreads();
    if (tid == 0)
        bcast = 0.5f * ((wave_part2[0] + wave_part2[1] +
                         wave_part2[2] + wave_part2[3]) * INV_TOTAL);
    __syncthreads();
    out[tid] = bcast;
}

// ---- Path B (fallback): proven two-kernel version -------------------------
__global__ __launch_bounds__(256) void conv_sig_partial(
    const float* __restrict__ data, const float* __restrict__ w,
    const float* __restrict__ bias, float* __restrict__ ws)
{
    const float p = conv_partial(data, w, bias);
    if (threadIdx.x == 0) ws[blockIdx.x] = p;
}

__global__ __launch_bounds__(256) void reduce_broadcast(
    const float* __restrict__ ws, float* __restrict__ out)
{
    __shared__ float wave_part[4];
    __shared__ float result;

    const int tid = threadIdx.x;
    float acc = ws[tid];
    #pragma unroll
    for (int off = 32; off > 0; off >>= 1)
        acc += __shfl_down(acc, off, 64);
    if ((tid & 63) == 0) wave_part[tid >> 6] = acc;
    __syncthreads();
    if (tid == 0) {
        float total = wave_part[0] + wave_part[1] + wave_part[2] + wave_part[3];
        result = 0.5f * (total * INV_TOTAL);
    }
    __syncthreads();
    out[tid] = result;
}

extern "C" void kernel_launch(void* const* d_in, const int* in_sizes, int n_in,
                              void* d_out, int out_size, void* d_ws, size_t ws_size,
                              hipStream_t stream)
{
    const float* data = (const float*)d_in[0];   // (256,1,64,64) f32
    const float* w    = (const float*)d_in[1];   // (1,1,4,4) f32
    const float* bias = (const float*)d_in[2];   // (1,) f32
    float* out = (float*)d_out;                  // 256 f32
    float* ws  = (float*)d_ws;                   // 256 partials, all overwritten

    void* args[] = { (void*)&data, (void*)&w, (void*)&bias,
                     (void*)&ws, (void*)&out };
    hipError_t err = hipLaunchCooperativeKernel(
        (void*)conv_sig_coop, dim3(BATCH), dim3(256), args, 0, stream);

    if (err != hipSuccess) {
        // Known-good two-dispatch fallback.
        conv_sig_partial<<<BATCH, 256, 0, stream>>>(data, w, bias, ws);
        reduce_broadcast<<<1, 256, 0, stream>>>(ws, out);
    }
}

// Round 3
// 61.610 us; speedup vs baseline: 1.5064x; 1.5064x over previous
//
#include <hip/hip_runtime.h>

// out[0..255] = 0.5 * mean(sigmoid(conv2d_valid(data, w4x4) + b))
// Quantum term is identically 0: RX(pi) = -i*X acts as a global phase on the
// uniform H^16|0> state, CX is a basis permutation -> uniform probs ->
// 2*P(q0=1)-1 = 0 exactly.
//
// REVERT to the proven two-dispatch structure (60.1 us, round 0).
// Single-dispatch attempts are empirically closed on this harness:
//   * tagged-spin fusion (round 1): container failure (hang risk).
//   * hipLaunchCooperativeKernel + grid.sync() (round 2): 92.8 us --
//     coop launch takes a slow non-graph-node replay path and the grid
//     barrier serializes on stragglers; +33 us vs two plain graph nodes.
// Timed iteration = ~41 us harness 256 MB workspace poison fill (80% of
// HBM peak, untouchable) + ~7 us our two kernels + graph node gaps.
//
// k1: 256 blocks, block b -> ws[b] = partial sigmoid-sum of image b.
//     4 adjacent pixels per step via two aligned float4 LDS reads per kernel
//     row (8x ds_read_b128 + 64 FMA per group vs 64 scalar reads).
// k2: 1 block, reduce 256 partials, broadcast to out[0..255].

constexpr int IMG   = 64;
constexpr int OUTW  = 61;                   // 64 - 4 + 1
constexpr int NPIX  = OUTW * OUTW;          // 3721
constexpr int BATCH = 256;
constexpr int GPR   = 16;                   // 4-pixel groups per row (j0 = 4g)
constexpr int NGRP  = OUTW * GPR;           // 976
constexpr float INV_TOTAL = 1.0f / (float)(BATCH * NPIX);

__device__ __forceinline__ float sigf(float s) {
    return __builtin_amdgcn_rcpf(1.0f + __expf(-s));
}

__global__ __launch_bounds__(256) void conv_sig_partial(
    const float* __restrict__ data, const float* __restrict__ w,
    const float* __restrict__ bias, float* __restrict__ ws)
{
    __shared__ __align__(16) float img[IMG * IMG + 4];  // +4 pad: g=15 second f4
    __shared__ float wsm[16];
    __shared__ float wave_part[4];

    const int tid = threadIdx.x;

    // Stage image: 1024 float4 over 256 threads (coalesced 16B/lane).
    const float* src = data + (size_t)blockIdx.x * (IMG * IMG);
    #pragma unroll
    for (int i = 0; i < 4; ++i)
        reinterpret_cast<float4*>(img)[tid + 256 * i] =
            reinterpret_cast<const float4*>(src)[tid + 256 * i];
    if (tid < 16) wsm[tid] = w[tid];
    if (tid >= 16 && tid < 20) img[IMG * IMG + tid - 16] = 0.0f;  // pad
    __syncthreads();

    // Weights to registers (uniform LDS reads broadcast, conflict-free).
    float wr[16];
    #pragma unroll
    for (int k = 0; k < 16; ++k) wr[k] = wsm[k];
    const float b0 = bias[0];

    const float4* imgv = reinterpret_cast<const float4*>(img);
    float acc = 0.0f;

    for (int gidx = tid; gidx < NGRP; gidx += 256) {
        const int i = gidx >> 4;          // output row
        const int g = gidx & 15;          // 4-pixel group; j0 = 4g
        float s0 = b0, s1 = b0, s2 = b0, s3 = b0;
        #pragma unroll
        for (int ki = 0; ki < 4; ++ki) {
            const int rb = (i + ki) * (IMG / 4) + g;
            const float4 a = imgv[rb];        // cols 4g .. 4g+3
            const float4 c = imgv[rb + 1];    // cols 4g+4 .. 4g+7 (pad-safe)
            const float w0 = wr[ki * 4 + 0], w1 = wr[ki * 4 + 1];
            const float w2 = wr[ki * 4 + 2], w3 = wr[ki * 4 + 3];
            s0 = fmaf(a.x, w0, fmaf(a.y, w1, fmaf(a.z, w2, fmaf(a.w, w3, s0))));
            s1 = fmaf(a.y, w0, fmaf(a.z, w1, fmaf(a.w, w2, fmaf(c.x, w3, s1))));
            s2 = fmaf(a.z, w0, fmaf(a.w, w1, fmaf(c.x, w2, fmaf(c.y, w3, s2))));
            s3 = fmaf(a.w, w0, fmaf(c.x, w1, fmaf(c.y, w2, fmaf(c.z, w3, s3))));
        }
        if (g == 15) {                    // j0=60: only pixel 0 in range (OUTW=61)
            acc += sigf(s0);
        } else {
            acc += sigf(s0) + sigf(s1) + sigf(s2) + sigf(s3);
        }
    }

    // Wave-64 shuffle reduction, then cross-wave via LDS.
    #pragma unroll
    for (int off = 32; off > 0; off >>= 1)
        acc += __shfl_down(acc, off, 64);
    if ((tid & 63) == 0) wave_part[tid >> 6] = acc;
    __syncthreads();

    if (tid == 0)
        ws[blockIdx.x] = wave_part[0] + wave_part[1] + wave_part[2] + wave_part[3];
}

__global__ __launch_bounds__(256) void reduce_broadcast(
    const float* __restrict__ ws, float* __restrict__ out)
{
    __shared__ float wave_part[4];
    __shared__ float result;

    const int tid = threadIdx.x;
    float acc = ws[tid];
    #pragma unroll
    for (int off = 32; off > 0; off >>= 1)
        acc += __shfl_down(acc, off, 64);
    if ((tid & 63) == 0) wave_part[tid >> 6] = acc;
    __syncthreads();
    if (tid == 0) {
        float total = wave_part[0] + wave_part[1] + wave_part[2] + wave_part[3];
        result = 0.5f * (total * INV_TOTAL);
    }
    __syncthreads();
    out[tid] = result;
}

extern "C" void kernel_launch(void* const* d_in, const int* in_sizes, int n_in,
                              void* d_out, int out_size, void* d_ws, size_t ws_size,
                              hipStream_t stream)
{
    const float* data = (const float*)d_in[0];   // (256,1,64,64) f32
    const float* w    = (const float*)d_in[1];   // (1,1,4,4) f32
    const float* bias = (const float*)d_in[2];   // (1,) f32
    float* out = (float*)d_out;                  // 256 f32
    float* ws  = (float*)d_ws;                   // 256 partials, all overwritten

    conv_sig_partial<<<BATCH, 256, 0, stream>>>(data, w, bias, ws);
    reduce_broadcast<<<1, 256, 0, stream>>>(ws, out);
}